// Round 4
// baseline (448.178 us; speedup 1.0000x reference)
//
#include <hip/hip_runtime.h>

// Problem constants (fixed by setup_inputs)
constexpr int K_ = 64, D_ = 9, E_ = 10;
constexpr int A1_ = 3, A2_ = 8, A3_ = 18, A_ = 29;
constexpr int NP2 = 45;            // sorted pairs (i<=j) of 9
constexpr int NP3 = 165;           // sorted triples (i<=j<=l) of 9
constexpr int S3N = NP3 * D_;      // 1485
constexpr int S2N = NP2 * D_;      // 405
constexpr int C1N = D_ * D_;       // 81
constexpr int TBL = S3N + S2N + C1N;   // 1971 floats
constexpr int NORD3 = D_ * D_ * D_;    // 729 ordered triples
constexpr int NORD2 = D_ * D_;         // 81 ordered pairs
constexpr int SLICE = 2048;            // ws floats per block (8 KB, private)

// B3[i] = number of sorted triples whose first element < i
__device__ const int B3TAB[D_] = {0, 45, 81, 109, 130, 145, 155, 161, 164};

// sorted-triple index for sort(a,b,g)=(i<=j<=l): t = B3[i] + (19-i-j)(j-i)/2 + (l-j)
__device__ __forceinline__ int trip_index(int a, int b, int g) {
  int i = min(a, b), j = max(a, b);
  int t0 = min(j, g); int l = max(j, g); j = t0;
  t0 = min(i, j); j = max(i, j); i = t0;
  return B3TAB[i] + ((19 - i - j) * (j - i)) / 2 + (l - j);
}
// sorted-pair index for i<=j:  p = i*9 - i*(i-1)/2 + (j-i)
__device__ __forceinline__ int pair_index(int a, int b) {
  int i = min(a, b), j = max(a, b);
  return i * D_ - (i * (i - 1)) / 2 + (j - i);
}

// ---------------------------------------------------------------------------
// Single kernel. Block = one (e,k), 256 threads.
// Phase 0: wp[b] = sum_a w[e,a,k]*proj[a,b]               (small LDS, proven)
// Phase 1: build symmetrized S3/S2/C1 table in LDS from raw U1/U2/U3
//          (R3-verified logic: ordered loop + closed-form sorted index).
// Spill:   copy table to this block's PRIVATE global ws slice.
// Phase 2: per-n polynomial reading the GLOBAL slice (R1-proven load path).
// ---------------------------------------------------------------------------
__global__ __launch_bounds__(256) void fused_kernel(
    const float* __restrict__ x, const int* __restrict__ counts,
    const float* __restrict__ w, const float* __restrict__ proj,
    const float* __restrict__ U1, const float* __restrict__ U2,
    const float* __restrict__ U3, float* ws, float* __restrict__ out) {
  const int ek = blockIdx.x;
  const int e = ek / K_, k = ek % K_;
  const int tid = threadIdx.x;

  __shared__ float wp[32];
  __shared__ float tbl[TBL];

  for (int idx = tid; idx < TBL; idx += 256) tbl[idx] = 0.f;
  if (tid < A_) {
    float acc = 0.f;
    #pragma unroll
    for (int a = 0; a < A_; ++a)
      acc = fmaf(w[(e * A_ + a) * K_ + k], proj[a * A_ + tid], acc);
    wp[tid] = acc;
  }
  __syncthreads();

  // ---- Phase 1: table build (verbatim R3) ----
  const int W3 = NORD3 * D_;           // 6561 items: (o, ordered triple n)
  const int W2 = NORD2 * D_;           // 729 items:  (o, ordered pair n)
  const int WORK = W3 + W2 + C1N;
  for (int it = tid; it < WORK; it += 256) {
    if (it < W3) {
      int o = it / NORD3, n = it % NORD3;
      const float2* u = reinterpret_cast<const float2*>(U3 + (o * NORD3 + n) * A3_);
      float acc = 0.f;
      #pragma unroll
      for (int m = 0; m < A3_ / 2; ++m) {
        float2 v = u[m];
        acc = fmaf(v.x, wp[A1_ + A2_ + 2 * m], acc);
        acc = fmaf(v.y, wp[A1_ + A2_ + 2 * m + 1], acc);
      }
      int a = n / 81, r = n % 81, b = r / 9, g = r % 9;
      atomicAdd(&tbl[trip_index(a, b, g) * D_ + o], acc);
    } else if (it < W3 + W2) {
      int id = it - W3;
      int o = id / NORD2, n = id % NORD2;
      const float4* u = reinterpret_cast<const float4*>(U2 + (o * NORD2 + n) * A2_);
      float4 v0 = u[0], v1 = u[1];
      float acc = v0.x * wp[A1_ + 0];
      acc = fmaf(v0.y, wp[A1_ + 1], acc);
      acc = fmaf(v0.z, wp[A1_ + 2], acc);
      acc = fmaf(v0.w, wp[A1_ + 3], acc);
      acc = fmaf(v1.x, wp[A1_ + 4], acc);
      acc = fmaf(v1.y, wp[A1_ + 5], acc);
      acc = fmaf(v1.z, wp[A1_ + 6], acc);
      acc = fmaf(v1.w, wp[A1_ + 7], acc);
      int a = n / 9, b = n % 9;
      atomicAdd(&tbl[S3N + pair_index(a, b) * D_ + o], acc);
    } else {
      int id = it - W3 - W2;
      int o = id / D_, i = id % D_;
      const float* u = U1 + (o * D_ + i) * A1_;
      float acc = u[0] * wp[0];
      acc = fmaf(u[1], wp[1], acc);
      acc = fmaf(u[2], wp[2], acc);
      tbl[S3N + S2N + i * D_ + o] = acc;   // unique writer: plain store
    }
  }
  __syncthreads();

  // ---- Spill table to this block's private global slice ----
  float* g = ws + (size_t)ek * SLICE;
  for (int idx = tid; idx < TBL; idx += 256) g[idx] = tbl[idx];
  __syncthreads();                      // drains vmcnt before barrier
  asm volatile("" ::: "memory");        // keep phase 2 reading memory, not LDS

  // ---- Phase 2: per-n polynomial, R1-proven GLOBAL load path ----
  if (tid >= 128) return;               // no barriers below

  int start = 0;
  for (int s = 0; s < e; ++s) start += counts[s];
  int cnt = counts[e];
  bool active = tid < cnt;
  int n = start + tid;
  int nc = active ? n : start;          // clamp for safe loads
  const float* xp = x + (nc * K_ + k) * D_;
  float xv[D_];
  #pragma unroll
  for (int l = 0; l < D_; ++l) xv[l] = xp[l];

  const float* s3 = g;
  const float* s2 = g + S3N;
  const float* c1 = g + S3N + S2N;

  float acc[D_];
  #pragma unroll
  for (int o = 0; o < D_; ++o) acc[o] = 0.f;

  int t = 0, p = 0;
  #pragma unroll
  for (int i = 0; i < D_; ++i) {
    float xi = xv[i];
    #pragma unroll
    for (int o = 0; o < D_; ++o) acc[o] = fmaf(c1[i * D_ + o], xi, acc[o]);
    #pragma unroll
    for (int j = i; j < D_; ++j) {
      float xij = xi * xv[j];
      #pragma unroll
      for (int o = 0; o < D_; ++o) acc[o] = fmaf(s2[p * D_ + o], xij, acc[o]);
      ++p;
      #pragma unroll
      for (int l = j; l < D_; ++l) {
        float xijl = xij * xv[l];
        #pragma unroll
        for (int o = 0; o < D_; ++o) acc[o] = fmaf(s3[t * D_ + o], xijl, acc[o]);
        ++t;
      }
    }
  }

  if (active) {
    float* op = out + (n * K_ + k) * D_;
    #pragma unroll
    for (int o = 0; o < D_; ++o) op[o] = acc[o];
  }
}

// ---------------------------------------------------------------------------
extern "C" void kernel_launch(void* const* d_in, const int* in_sizes, int n_in,
                              void* d_out, int out_size, void* d_ws, size_t ws_size,
                              hipStream_t stream) {
  const float* x    = (const float*)d_in[0];
  const int*   cnts = (const int*)  d_in[1];
  const float* w    = (const float*)d_in[2];
  const float* proj = (const float*)d_in[3];
  const float* U1   = (const float*)d_in[4];
  const float* U2   = (const float*)d_in[5];
  const float* U3   = (const float*)d_in[6];
  float* out = (float*)d_out;
  float* ws  = (float*)d_ws;   // uses E_*K_*SLICE*4 = 5.24 MB, block-private slices

  fused_kernel<<<E_ * K_, 256, 0, stream>>>(x, cnts, w, proj, U1, U2, U3, ws, out);
}

// Round 5
// 364.468 us; speedup vs baseline: 1.2297x; 1.2297x over previous
//
#include <hip/hip_runtime.h>

// Problem constants (fixed by setup_inputs)
constexpr int K_ = 64, D_ = 9, E_ = 10;
constexpr int A1_ = 3, A2_ = 8, A3_ = 18, A_ = 29;
constexpr int NP2 = 45;            // sorted pairs (i<=j) of 9
constexpr int NP3 = 165;           // sorted triples (i<=j<=l) of 9
constexpr int S3N = NP3 * D_;      // 1485
constexpr int S2N = NP2 * D_;      // 405
constexpr int C1N = D_ * D_;       // 81
constexpr int TBL = S3N + S2N + C1N;   // 1971 floats

// Workspace layout (float offsets)
constexpr int OFF_WP  = 0;                    // E*A*K = 18560, layout [e][b][k]
constexpr int OFF_U3S = OFF_WP  + E_*A_*K_;   // A3*S3N = 26730, layout [m][t*9+o]
constexpr int OFF_U2S = OFF_U3S + A3_*S3N;    // A2*S2N = 3240,  layout [m][p*9+o]
constexpr int OFF_TBL = 49152;                // per-(e,k) tables, 640 slices
constexpr int SLICE   = 2048;                 // floats per slice (8 KB)

// ---------------------------------------------------------------------------
// Kernel 1 (prep): wp = einsum('zak,ab->zbk', w, proj)  [R1-proven math];
// symmetrized U3 -> U3S[m][t*9+o], U2 -> U2S[m][p*9+o]  (m-major so the
// fused kernel's table build reads lane-consecutive addresses).
// ---------------------------------------------------------------------------
__global__ void prep_kernel(const float* __restrict__ w,
                            const float* __restrict__ proj,
                            const float* __restrict__ U2,
                            const float* __restrict__ U3,
                            float* __restrict__ ws) {
  const int WP_N  = E_*A_*K_;
  const int U3S_N = A3_*S3N;
  const int U2S_N = A2_*S2N;
  int idx = blockIdx.x * blockDim.x + threadIdx.x;
  if (idx < WP_N) {
    int e = idx / (A_*K_); int r = idx % (A_*K_); int b = r / K_; int k = r % K_;
    float acc = 0.f;
    for (int a = 0; a < A_; ++a)
      acc = fmaf(w[(e*A_ + a)*K_ + k], proj[a*A_ + b], acc);
    ws[OFF_WP + idx] = acc;
  } else if (idx < WP_N + U3S_N) {
    int id = idx - WP_N;
    int t = id / (D_*A3_); int r = id % (D_*A3_); int o = r / A3_; int m = r % A3_;
    // decode sorted triple index t -> (i<=j<=l)
    int ti = 0, tj = 0, tl = 0, c = 0;
    for (int a = 0; a < D_; ++a)
      for (int b = a; b < D_; ++b)
        for (int g = b; g < D_; ++g) { if (c == t) { ti = a; tj = b; tl = g; } ++c; }
    auto u3 = [&](int a, int b, int g) {
      return U3[(((o*D_ + a)*D_ + b)*D_ + g)*A3_ + m];
    };
    float s;
    if (ti == tj && tj == tl)      s = u3(ti, ti, ti);
    else if (ti == tj)             s = u3(ti, ti, tl) + u3(ti, tl, ti) + u3(tl, ti, ti);
    else if (tj == tl)             s = u3(ti, tj, tj) + u3(tj, ti, tj) + u3(tj, tj, ti);
    else                           s = u3(ti, tj, tl) + u3(ti, tl, tj) + u3(tj, ti, tl)
                                     + u3(tj, tl, ti) + u3(tl, ti, tj) + u3(tl, tj, ti);
    ws[OFF_U3S + m*S3N + t*D_ + o] = s;          // transposed store
  } else if (idx < WP_N + U3S_N + U2S_N) {
    int id = idx - WP_N - U3S_N;
    int p = id / (D_*A2_); int r = id % (D_*A2_); int o = r / A2_; int m = r % A2_;
    int pi = 0, pj = 0, c = 0;
    for (int a = 0; a < D_; ++a)
      for (int b = a; b < D_; ++b) { if (c == p) { pi = a; pj = b; } ++c; }
    float s = U2[((o*D_ + pi)*D_ + pj)*A2_ + m];
    if (pi != pj) s += U2[((o*D_ + pj)*D_ + pi)*A2_ + m];
    ws[OFF_U2S + m*S2N + p*D_ + o] = s;          // transposed store
  }
}

// ---------------------------------------------------------------------------
// Kernel 2 (fused): block = one (e,k), 128 threads.
// Build: table elem idx has a UNIQUE writer thread; coalesced m-major reads
//        (L2-hot 120 KB shared by all 640 blocks); store straight to the
//        block-private global slice (no LDS table, no atomics).
// Phase 2: per-n polynomial reading the GLOBAL slice (R1/R4-proven path).
// ---------------------------------------------------------------------------
__global__ __launch_bounds__(128) void fused_kernel(
    const float* __restrict__ x, const int* __restrict__ counts,
    const float* __restrict__ U1, float* __restrict__ ws,
    float* __restrict__ out) {
  const int ek = blockIdx.x;
  const int e = ek / K_, k = ek % K_;
  const int tid = threadIdx.x;

  __shared__ float wpk[32];
  if (tid < A_) wpk[tid] = ws[OFF_WP + (e*A_ + tid)*K_ + k];
  __syncthreads();

  const float* u3s = ws + OFF_U3S;
  const float* u2s = ws + OFF_U2S;
  float* g = ws + OFF_TBL + (size_t)ek * SLICE;

  for (int idx = tid; idx < TBL; idx += 128) {
    float acc = 0.f;
    if (idx < S3N) {
      #pragma unroll
      for (int m = 0; m < A3_; ++m)
        acc = fmaf(u3s[m*S3N + idx], wpk[A1_ + A2_ + m], acc);
    } else if (idx < S3N + S2N) {
      int id = idx - S3N;
      #pragma unroll
      for (int m = 0; m < A2_; ++m)
        acc = fmaf(u2s[m*S2N + id], wpk[A1_ + m], acc);
    } else {
      int id = idx - S3N - S2N;
      int i = id / D_, o = id % D_;
      #pragma unroll
      for (int m = 0; m < A1_; ++m)
        acc = fmaf(U1[(o*D_ + i)*A1_ + m], wpk[m], acc);
    }
    g[idx] = acc;
  }
  __syncthreads();                      // drains vmcnt: table visible to block
  asm volatile("" ::: "memory");

  // ---- Phase 2: per-n polynomial, R1/R4-proven GLOBAL load path ----
  int start = 0;
  for (int s = 0; s < e; ++s) start += counts[s];
  int cnt = counts[e];
  bool active = tid < cnt;
  int n = start + tid;
  int nc = active ? n : start;          // clamp for safe loads
  const float* xp = x + (nc * K_ + k) * D_;
  float xv[D_];
  #pragma unroll
  for (int l = 0; l < D_; ++l) xv[l] = xp[l];

  const float* s3 = g;
  const float* s2 = g + S3N;
  const float* c1 = g + S3N + S2N;

  float acc[D_];
  #pragma unroll
  for (int o = 0; o < D_; ++o) acc[o] = 0.f;

  int t = 0, p = 0;
  #pragma unroll
  for (int i = 0; i < D_; ++i) {
    float xi = xv[i];
    #pragma unroll
    for (int o = 0; o < D_; ++o) acc[o] = fmaf(c1[i * D_ + o], xi, acc[o]);
    #pragma unroll
    for (int j = i; j < D_; ++j) {
      float xij = xi * xv[j];
      #pragma unroll
      for (int o = 0; o < D_; ++o) acc[o] = fmaf(s2[p * D_ + o], xij, acc[o]);
      ++p;
      #pragma unroll
      for (int l = j; l < D_; ++l) {
        float xijl = xij * xv[l];
        #pragma unroll
        for (int o = 0; o < D_; ++o) acc[o] = fmaf(s3[t * D_ + o], xijl, acc[o]);
        ++t;
      }
    }
  }

  if (active) {
    float* op = out + (n * K_ + k) * D_;
    #pragma unroll
    for (int o = 0; o < D_; ++o) op[o] = acc[o];
  }
}

// ---------------------------------------------------------------------------
extern "C" void kernel_launch(void* const* d_in, const int* in_sizes, int n_in,
                              void* d_out, int out_size, void* d_ws, size_t ws_size,
                              hipStream_t stream) {
  const float* x    = (const float*)d_in[0];
  const int*   cnts = (const int*)  d_in[1];
  const float* w    = (const float*)d_in[2];
  const float* proj = (const float*)d_in[3];
  const float* U1   = (const float*)d_in[4];
  const float* U2   = (const float*)d_in[5];
  const float* U3   = (const float*)d_in[6];
  float* out = (float*)d_out;
  float* ws  = (float*)d_ws;   // uses OFF_TBL*4 + 640*SLICE*4 ~= 5.4 MB

  const int PREP_N = E_*A_*K_ + A3_*S3N + A2_*S2N;   // 48530
  int prep_blocks = (PREP_N + 255) / 256;
  prep_kernel<<<prep_blocks, 256, 0, stream>>>(w, proj, U2, U3, ws);
  fused_kernel<<<E_ * K_, 128, 0, stream>>>(x, cnts, U1, ws, out);
}

// Round 6
// 117.997 us; speedup vs baseline: 3.7982x; 3.0888x over previous
//
#include <hip/hip_runtime.h>

// Problem constants (fixed by setup_inputs)
constexpr int K_ = 64, D_ = 9, E_ = 10;
constexpr int A1_ = 3, A2_ = 8, A3_ = 18, A_ = 29;
constexpr int NP2 = 45;            // sorted pairs (i<=j) of 9
constexpr int NP3 = 165;           // sorted triples (i<=j<=l) of 9
constexpr int S3N = NP3 * D_;      // 1485
constexpr int S2N = NP2 * D_;      // 405
constexpr int C1N = D_ * D_;       // 81
constexpr int TBL = S3N + S2N + C1N;   // 1971 floats

// Workspace layout (float offsets)
constexpr int OFF_WP  = 0;                    // E*A*K = 18560, layout [e][b][k]
constexpr int OFF_U3S = OFF_WP  + E_*A_*K_;   // A3*S3N = 26730, layout [m][t*9+o]
constexpr int OFF_U2S = OFF_U3S + A3_*S3N;    // A2*S2N = 3240,  layout [m][p*9+o]
constexpr int OFF_TBL = 49152;                // per-(e,k) tables, 640 slices
constexpr int SLICE   = 2048;                 // floats per slice (8 KB)

// ---------------------------------------------------------------------------
// Kernel 1 (prep, R1/R5-proven): wp = einsum('zak,ab->zbk', w, proj);
// symmetrized U3 -> U3S[m][t*9+o], U2 -> U2S[m][p*9+o]  (m-major: the build
// kernel's reads are lane-consecutive).
// ---------------------------------------------------------------------------
__global__ void prep_kernel(const float* __restrict__ w,
                            const float* __restrict__ proj,
                            const float* __restrict__ U2,
                            const float* __restrict__ U3,
                            float* __restrict__ ws) {
  const int WP_N  = E_*A_*K_;
  const int U3S_N = A3_*S3N;
  const int U2S_N = A2_*S2N;
  int idx = blockIdx.x * blockDim.x + threadIdx.x;
  if (idx < WP_N) {
    int e = idx / (A_*K_); int r = idx % (A_*K_); int b = r / K_; int k = r % K_;
    float acc = 0.f;
    for (int a = 0; a < A_; ++a)
      acc = fmaf(w[(e*A_ + a)*K_ + k], proj[a*A_ + b], acc);
    ws[OFF_WP + idx] = acc;
  } else if (idx < WP_N + U3S_N) {
    int id = idx - WP_N;
    int t = id / (D_*A3_); int r = id % (D_*A3_); int o = r / A3_; int m = r % A3_;
    int ti = 0, tj = 0, tl = 0, c = 0;
    for (int a = 0; a < D_; ++a)
      for (int b = a; b < D_; ++b)
        for (int g = b; g < D_; ++g) { if (c == t) { ti = a; tj = b; tl = g; } ++c; }
    auto u3 = [&](int a, int b, int g) {
      return U3[(((o*D_ + a)*D_ + b)*D_ + g)*A3_ + m];
    };
    float s;
    if (ti == tj && tj == tl)      s = u3(ti, ti, ti);
    else if (ti == tj)             s = u3(ti, ti, tl) + u3(ti, tl, ti) + u3(tl, ti, ti);
    else if (tj == tl)             s = u3(ti, tj, tj) + u3(tj, ti, tj) + u3(tj, tj, ti);
    else                           s = u3(ti, tj, tl) + u3(ti, tl, tj) + u3(tj, ti, tl)
                                     + u3(tj, tl, ti) + u3(tl, ti, tj) + u3(tl, tj, ti);
    ws[OFF_U3S + m*S3N + t*D_ + o] = s;
  } else if (idx < WP_N + U3S_N + U2S_N) {
    int id = idx - WP_N - U3S_N;
    int p = id / (D_*A2_); int r = id % (D_*A2_); int o = r / A2_; int m = r % A2_;
    int pi = 0, pj = 0, c = 0;
    for (int a = 0; a < D_; ++a)
      for (int b = a; b < D_; ++b) { if (c == p) { pi = a; pj = b; } ++c; }
    float s = U2[((o*D_ + pi)*D_ + pj)*A2_ + m];
    if (pi != pj) s += U2[((o*D_ + pj)*D_ + pi)*A2_ + m];
    ws[OFF_U2S + m*S2N + p*D_ + o] = s;
  }
}

// ---------------------------------------------------------------------------
// Kernel 2 (build, R5-proven): block = one (e,k), 128 threads. Coalesced
// m-major reads (120 KB, L2-hot across 640 blocks); each table element has a
// unique writer -> plain stores to the block-private slice.
// ---------------------------------------------------------------------------
__global__ __launch_bounds__(128) void build_kernel(const float* __restrict__ U1,
                                                    float* __restrict__ ws) {
  const int ek = blockIdx.x;
  const int e = ek / K_, k = ek % K_;
  const int tid = threadIdx.x;

  __shared__ float wpk[32];
  if (tid < A_) wpk[tid] = ws[OFF_WP + (e*A_ + tid)*K_ + k];
  __syncthreads();

  const float* u3s = ws + OFF_U3S;
  const float* u2s = ws + OFF_U2S;
  float* g = ws + OFF_TBL + (size_t)ek * SLICE;

  for (int idx = tid; idx < TBL; idx += 128) {
    float acc = 0.f;
    if (idx < S3N) {
      #pragma unroll
      for (int m = 0; m < A3_; ++m)
        acc = fmaf(u3s[m*S3N + idx], wpk[A1_ + A2_ + m], acc);
    } else if (idx < S3N + S2N) {
      int id = idx - S3N;
      #pragma unroll
      for (int m = 0; m < A2_; ++m)
        acc = fmaf(u2s[m*S2N + id], wpk[A1_ + m], acc);
    } else {
      int id = idx - S3N - S2N;
      int i = id / D_, o = id % D_;
      #pragma unroll
      for (int m = 0; m < A1_; ++m)
        acc = fmaf(U1[(o*D_ + i)*A1_ + m], wpk[m], acc);
    }
    g[idx] = acc;
  }
}

// ---------------------------------------------------------------------------
// Kernel 3 (main, R1-proven): block = one (e,k), thread = one n.
// Tables arrive via const __restrict__ from a PREVIOUS kernel -> wave-uniform
// addresses become s_load (SGPR broadcast) -> no VGPR pressure, no spill.
// out[o] = sum_i C1[i,o] x_i + sum_{p=(i<=j)} S2[p,o] x_i x_j
//        + sum_{t=(i<=j<=l)} S3[t,o] x_i x_j x_l
// ---------------------------------------------------------------------------
__global__ __launch_bounds__(128) void main_kernel(const float* __restrict__ x,
                                                   const int* __restrict__ counts,
                                                   const float* __restrict__ ws,
                                                   float* __restrict__ out) {
  int ek = blockIdx.x;
  int e = ek / K_, k = ek % K_;
  int start = 0;
  for (int s = 0; s < e; ++s) start += counts[s];
  int cnt = counts[e];
  int tid = threadIdx.x;
  bool active = tid < cnt;
  int n = start + tid;
  int nc = active ? n : start;            // clamp for safe loads
  const float* xp = x + (nc*K_ + k)*D_;
  float xv[D_];
  #pragma unroll
  for (int l = 0; l < D_; ++l) xv[l] = xp[l];

  const float* s3 = ws + OFF_TBL + (size_t)ek * SLICE;
  const float* s2 = s3 + S3N;
  const float* c1 = s3 + S3N + S2N;

  float acc[D_];
  #pragma unroll
  for (int o = 0; o < D_; ++o) acc[o] = 0.f;

  int t = 0, p = 0;
  #pragma unroll
  for (int i = 0; i < D_; ++i) {
    float xi = xv[i];
    #pragma unroll
    for (int o = 0; o < D_; ++o) acc[o] = fmaf(c1[i*D_ + o], xi, acc[o]);
    #pragma unroll
    for (int j = i; j < D_; ++j) {
      float xij = xi * xv[j];
      #pragma unroll
      for (int o = 0; o < D_; ++o) acc[o] = fmaf(s2[p*D_ + o], xij, acc[o]);
      ++p;
      #pragma unroll
      for (int l = j; l < D_; ++l) {
        float xijl = xij * xv[l];
        #pragma unroll
        for (int o = 0; o < D_; ++o) acc[o] = fmaf(s3[t*D_ + o], xijl, acc[o]);
        ++t;
      }
    }
  }

  if (active) {
    float* op = out + (n*K_ + k)*D_;
    #pragma unroll
    for (int o = 0; o < D_; ++o) op[o] = acc[o];
  }
}

// ---------------------------------------------------------------------------
extern "C" void kernel_launch(void* const* d_in, const int* in_sizes, int n_in,
                              void* d_out, int out_size, void* d_ws, size_t ws_size,
                              hipStream_t stream) {
  const float* x    = (const float*)d_in[0];
  const int*   cnts = (const int*)  d_in[1];
  const float* w    = (const float*)d_in[2];
  const float* proj = (const float*)d_in[3];
  const float* U1   = (const float*)d_in[4];
  const float* U2   = (const float*)d_in[5];
  const float* U3   = (const float*)d_in[6];
  float* out = (float*)d_out;
  float* ws  = (float*)d_ws;   // uses (OFF_TBL + 640*SLICE)*4 ~= 5.4 MB

  const int PREP_N = E_*A_*K_ + A3_*S3N + A2_*S2N;   // 48530
  int prep_blocks = (PREP_N + 255) / 256;
  prep_kernel<<<prep_blocks, 256, 0, stream>>>(w, proj, U2, U3, ws);
  build_kernel<<<E_ * K_, 128, 0, stream>>>(U1, ws);
  main_kernel<<<E_ * K_, 128, 0, stream>>>(x, cnts, ws, out);
}